// Round 9
// baseline (234.893 us; speedup 1.0000x reference)
//
#include <hip/hip_runtime.h>
#include <hip/hip_cooperative_groups.h>
#include <hip/hip_bf16.h>
#include <math.h>

namespace cg = cooperative_groups;

#define NN    20000
#define NK    160000          // NN*8
#define NEDGE 320000
#define HID   256
#define INFEAT 128
#define EPSF  1e-5f
#define CNB   256             // cooperative grid size (<= #CUs -> always co-resident)
#define NT1   313             // gemm/out tiles (64 rows each)

typedef __bf16  bf16x8 __attribute__((ext_vector_type(8)));
typedef float   f32x4  __attribute__((ext_vector_type(4)));
typedef ushort  u16x8  __attribute__((ext_vector_type(8)));

__device__ __forceinline__ float sigmoidf_(float x) { return 1.0f / (1.0f + expf(-x)); }

__device__ __forceinline__ ushort f2bf(float f) {
    __hip_bfloat16 h = __float2bfloat16(f);
    return __builtin_bit_cast(ushort, h);
}
__device__ __forceinline__ float bf2f(ushort u) {
    return __builtin_bit_cast(float, ((unsigned int)u) << 16);
}
__device__ __forceinline__ int wrapN(int v) {
    return (v < 0) ? v + NN : ((v >= NN) ? v - NN : v);
}

#define LDSP(p) ((__attribute__((address_space(3))) unsigned int*)(p))
#define GBLP(p) ((const __attribute__((address_space(1))) unsigned int*)(p))
#define GLD16(g, l) __builtin_amdgcn_global_load_lds(GBLP(g), LDSP(l), 16, 0, 0)

// ================= phase 0: prep (xab = agg(x); W1t; W2t), 127 blocks =========
__device__ __forceinline__ void phase_prep(int b, int t,
    const float* __restrict__ x, const float* __restrict__ W1, const float* __restrict__ W2,
    ushort* __restrict__ W1t, ushort* __restrict__ W2t, ushort* __restrict__ xab)
{
    const float inv17 = 1.0f / 17.0f;
    if (b < 79) {
        const int item = b * 512 + t;
        if (item < 40000) {
            const int strip = item >> 4, fg = item & 15;
            const int f0 = fg * 8;
            const int vstart = strip * 8;
            float S[8] = {};
            #pragma unroll
            for (int o = -8; o <= 8; ++o) {
                const float* r = x + (size_t)wrapN(vstart + o) * INFEAT + f0;
                const float4 a = *reinterpret_cast<const float4*>(r);
                const float4 c = *reinterpret_cast<const float4*>(r + 4);
                S[0] += a.x; S[1] += a.y; S[2] += a.z; S[3] += a.w;
                S[4] += c.x; S[5] += c.y; S[6] += c.z; S[7] += c.w;
            }
            for (int i = 0; i < 8; ++i) {
                const int v = vstart + i;
                const float* ra = x + (size_t)wrapN(v + 9) * INFEAT + f0;
                const float* rs = x + (size_t)wrapN(v - 8) * INFEAT + f0;
                const float4 a0 = *reinterpret_cast<const float4*>(ra);
                const float4 a1 = *reinterpret_cast<const float4*>(ra + 4);
                const float4 s0 = *reinterpret_cast<const float4*>(rs);
                const float4 s1 = *reinterpret_cast<const float4*>(rs + 4);
                u16x8 o;
                #pragma unroll
                for (int j = 0; j < 8; ++j) o[j] = f2bf(S[j] * inv17);
                *reinterpret_cast<u16x8*>(xab + (size_t)v * INFEAT + f0) = o;
                S[0] += a0.x - s0.x; S[1] += a0.y - s0.y; S[2] += a0.z - s0.z; S[3] += a0.w - s0.w;
                S[4] += a1.x - s1.x; S[5] += a1.y - s1.y; S[6] += a1.z - s1.z; S[7] += a1.w - s1.w;
            }
        }
    } else if (b < 95) {
        const int e = ((b - 79) * 512 + t) * 4;     // 32768 elements
        ushort4 o;
        #pragma unroll
        for (int j = 0; j < 4; ++j) {
            const int ee = e + j;
            const int n = ee >> 7, k = ee & 127;    // W1t[n][k] = W1[k][n]
            ((ushort*)&o)[j] = f2bf(W1[k * 256 + n]);
        }
        *reinterpret_cast<ushort4*>(W1t + e) = o;
    } else {
        const int e = ((b - 95) * 512 + t) * 4;     // 65536 elements
        ushort4 o;
        #pragma unroll
        for (int j = 0; j < 4; ++j) {
            const int ee = e + j;
            const int n = ee >> 8, k = ee & 255;    // W2t[n][k] = W2[k][n]
            ((ushort*)&o)[j] = f2bf(W2[k * 256 + n]);
        }
        *reinterpret_cast<ushort4*>(W2t + e) = o;
    }
}

// ================= phase 1: A = xab @ W1 + b1 (+BN partials), tile bb =========
__device__ __forceinline__ void phase_gemm1(int bb, int t, char* smem,
    const ushort* __restrict__ xab, const ushort* __restrict__ W1t,
    const float* __restrict__ b1, ushort* __restrict__ A, float* __restrict__ part)
{
    char* As = smem;
    char* Bs = smem + 8192;
    const int wave = t >> 6, lane = t & 63;
    const int wr = (wave >> 2) * 32;
    const int wc = (wave & 3) * 32;
    const int bm = bb * 64;
    f32x4 acc[2][2][2] = {};   // [ny][mi][ni]

    #pragma unroll
    for (int kt = 0; kt < 2; ++kt) {
        const int k0 = kt * 64;
        {   // stage A: 64x64 bf16
            const int c = wave * 64 + lane;
            const int row = c >> 3;
            const int lk = (c & 7) ^ (row & 7);
            int rg = bm + row; if (rg >= NN) rg = NN - 1;
            GLD16(xab + (size_t)rg * INFEAT + k0 + lk * 8, As + wave * 1024);
        }
        #pragma unroll
        for (int it = 0; it < 4; ++it) {   // stage B: 256x64
            const int cb = (it * 8 + wave) * 64 + lane;
            const int row = cb >> 3;
            const int lk = (cb & 7) ^ (row & 7);
            GLD16(W1t + (size_t)row * INFEAT + k0 + lk * 8, Bs + (it * 8 + wave) * 1024);
        }
        __syncthreads();
        #pragma unroll
        for (int kk = 0; kk < 2; ++kk) {
            const int klog = kk * 64 + ((lane >> 4) << 4);
            bf16x8 af[2];
            #pragma unroll
            for (int mi = 0; mi < 2; ++mi) {
                const int row = wr + mi * 16 + (lane & 15);
                af[mi] = *reinterpret_cast<const bf16x8*>(As + row * 128 + (klog ^ ((row & 7) << 4)));
            }
            #pragma unroll
            for (int ny = 0; ny < 2; ++ny)
                #pragma unroll
                for (int ni = 0; ni < 2; ++ni) {
                    const int row = ny * 128 + wc + ni * 16 + (lane & 15);
                    const bf16x8 bv = *reinterpret_cast<const bf16x8*>(Bs + row * 128 + (klog ^ ((row & 7) << 4)));
                    #pragma unroll
                    for (int mi = 0; mi < 2; ++mi)
                        acc[ny][mi][ni] = __builtin_amdgcn_mfma_f32_16x16x32_bf16(af[mi], bv, acc[ny][mi][ni], 0, 0, 0);
                }
        }
        __syncthreads();
    }

    // epilogue: bias, store A (bf16), BN partial sums (deterministic)
    float* sS  = (float*)smem;            // [8][64]
    float* s2S = (float*)(smem + 2048);   // [8][64]
    #pragma unroll
    for (int ny = 0; ny < 2; ++ny)
        #pragma unroll
        for (int ni = 0; ni < 2; ++ni) {
            const int colL = ny * 128 + wc + ni * 16 + (lane & 15);
            const float bv = b1[colL];
            float sv = 0.f, s2v = 0.f;
            #pragma unroll
            for (int mi = 0; mi < 2; ++mi)
                #pragma unroll
                for (int r = 0; r < 4; ++r) {
                    const int row = bm + wr + mi * 16 + ((lane >> 4) << 2) + r;
                    if (row < NN) {
                        const float val = acc[ny][mi][ni][r] + bv;
                        A[(size_t)row * 256 + colL] = f2bf(val);
                        sv += val; s2v += val * val;
                    }
                }
            sv  += __shfl_xor(sv, 16);  sv  += __shfl_xor(sv, 32);
            s2v += __shfl_xor(s2v, 16); s2v += __shfl_xor(s2v, 32);
            if (lane < 16) {
                sS [wave * 64 + ny * 32 + ni * 16 + lane] = sv;
                s2S[wave * 64 + ny * 32 + ni * 16 + lane] = s2v;
            }
        }
    __syncthreads();
    if (t < 256) {
        const int col = t;
        const int idx = (col >> 7) * 32 + ((col >> 4) & 1) * 16 + (col & 15);
        const int wcx = (col & 127) >> 5;
        part[(size_t)bb * 512 + col]       = sS [wcx * 64 + idx] + sS [(wcx + 4) * 64 + idx];
        part[(size_t)bb * 512 + 256 + col] = s2S[wcx * 64 + idx] + s2S[(wcx + 4) * 64 + idx];
    }
}

// ================= phase 2a/2b: BN reduce + finalize ==========================
__device__ __forceinline__ void phase_bnred(int b, int t,
    const float* __restrict__ part, float* __restrict__ part2)
{
    float s = 0.f;
    const int r0 = b * 10;
    const int r1 = (r0 + 10 < NT1) ? r0 + 10 : NT1;
    for (int r = r0; r < r1; ++r)
        s += part[(size_t)r * 512 + t];
    part2[(size_t)b * 512 + t] = s;
}

__device__ __forceinline__ void phase_bnfin(int t, char* smem,
    const float* __restrict__ part2, const float* __restrict__ gamma,
    const float* __restrict__ beta, float* __restrict__ ss)
{
    float tot = 0.f;
    #pragma unroll
    for (int j = 0; j < 32; ++j)
        tot += part2[(size_t)j * 512 + t];
    float* red = (float*)smem;
    red[t] = tot;
    __syncthreads();
    if (t < 256) {
        const float invn = 1.0f / (float)NN;
        const float mu   = red[t] * invn;
        const float var  = red[t + 256] * invn - mu * mu;
        const float sc   = gamma[t] * rsqrtf(var + EPSF);
        ss[t]       = sc;
        ss[256 + t] = beta[t] - mu * sc;
    }
}

// ================= phase 3: g = agg2(relu(bn(A))), 157 blocks =================
__device__ __forceinline__ void phase_mid(int b, int t,
    const ushort* __restrict__ A, const float* __restrict__ ss, ushort* __restrict__ g)
{
    const int fg = t & 31, nl = t >> 5;
    const int f0 = fg * 8;
    const int vstart = b * 128 + nl * 8;
    const float inv17 = 1.0f / 17.0f;
    float sc[8], sh[8];
    #pragma unroll
    for (int j = 0; j < 8; ++j) { sc[j] = ss[f0 + j]; sh[j] = ss[256 + f0 + j]; }
    float S[8] = {};
    #pragma unroll
    for (int o = -8; o <= 8; ++o) {
        const u16x8 h = *reinterpret_cast<const u16x8*>(A + (size_t)wrapN(vstart + o) * 256 + f0);
        #pragma unroll
        for (int j = 0; j < 8; ++j) S[j] += fmaxf(bf2f(h[j]) * sc[j] + sh[j], 0.f);
    }
    for (int i = 0; i < 8; ++i) {
        const int v = vstart + i;
        const u16x8 ha = *reinterpret_cast<const u16x8*>(A + (size_t)wrapN(v + 9) * 256 + f0);
        const u16x8 hs = *reinterpret_cast<const u16x8*>(A + (size_t)wrapN(v - 8) * 256 + f0);
        if (v < NN) {
            u16x8 o;
            #pragma unroll
            for (int j = 0; j < 8; ++j) o[j] = f2bf(S[j] * inv17);
            *reinterpret_cast<u16x8*>(g + (size_t)v * 256 + f0) = o;
        }
        #pragma unroll
        for (int j = 0; j < 8; ++j)
            S[j] += fmaxf(bf2f(ha[j]) * sc[j] + sh[j], 0.f)
                  - fmaxf(bf2f(hs[j]) * sc[j] + sh[j], 0.f);
    }
}

// ======== phase 4: h2 = relu(g@W2+b2), dots -> u,w (direct store), tile bb =====
__device__ __forceinline__ void phase_gemm2(int bb, int t, char* smem,
    const ushort* __restrict__ g, const ushort* __restrict__ W2t,
    const float* __restrict__ b2, const float* __restrict__ Wl,
    float* __restrict__ u, float* __restrict__ w)
{
    char* As = smem;
    char* Bs = smem + 8192;
    const int wave = t >> 6, lane = t & 63;
    const int wr = (wave >> 2) * 32;
    const int wc = (wave & 3) * 32;
    const int bm = bb * 64;
    f32x4 acc[2][2][2] = {};

    #pragma unroll
    for (int kt = 0; kt < 4; ++kt) {
        const int k0 = kt * 64;
        {
            const int c = wave * 64 + lane;
            const int row = c >> 3;
            const int lk = (c & 7) ^ (row & 7);
            int rg = bm + row; if (rg >= NN) rg = NN - 1;
            GLD16(g + (size_t)rg * 256 + k0 + lk * 8, As + wave * 1024);
        }
        #pragma unroll
        for (int it = 0; it < 4; ++it) {
            const int cb = (it * 8 + wave) * 64 + lane;
            const int row = cb >> 3;
            const int lk = (cb & 7) ^ (row & 7);
            GLD16(W2t + (size_t)row * 256 + k0 + lk * 8, Bs + (it * 8 + wave) * 1024);
        }
        __syncthreads();
        #pragma unroll
        for (int kk = 0; kk < 2; ++kk) {
            const int klog = kk * 64 + ((lane >> 4) << 4);
            bf16x8 af[2];
            #pragma unroll
            for (int mi = 0; mi < 2; ++mi) {
                const int row = wr + mi * 16 + (lane & 15);
                af[mi] = *reinterpret_cast<const bf16x8*>(As + row * 128 + (klog ^ ((row & 7) << 4)));
            }
            #pragma unroll
            for (int ny = 0; ny < 2; ++ny)
                #pragma unroll
                for (int ni = 0; ni < 2; ++ni) {
                    const int row = ny * 128 + wc + ni * 16 + (lane & 15);
                    const bf16x8 bv = *reinterpret_cast<const bf16x8*>(Bs + row * 128 + (klog ^ ((row & 7) << 4)));
                    #pragma unroll
                    for (int mi = 0; mi < 2; ++mi)
                        acc[ny][mi][ni] = __builtin_amdgcn_mfma_f32_16x16x32_bf16(af[mi], bv, acc[ny][mi][ni], 0, 0, 0);
                }
        }
        __syncthreads();
    }

    float b2v[2][2], wav[2][2], wbv[2][2];
    #pragma unroll
    for (int ny = 0; ny < 2; ++ny)
        #pragma unroll
        for (int ni = 0; ni < 2; ++ni) {
            const int col = ny * 128 + wc + ni * 16 + (lane & 15);
            b2v[ny][ni] = b2[col];
            wav[ny][ni] = Wl[col];
            wbv[ny][ni] = Wl[256 + col];
        }
    float* uW = (float*)smem;            // [4][64]
    float* wW = (float*)(smem + 1024);   // [4][64]
    #pragma unroll
    for (int mi = 0; mi < 2; ++mi)
        #pragma unroll
        for (int r = 0; r < 4; ++r) {
            float pu = 0.f, pw = 0.f;
            #pragma unroll
            for (int ny = 0; ny < 2; ++ny)
                #pragma unroll
                for (int ni = 0; ni < 2; ++ni) {
                    const float h = fmaxf(acc[ny][mi][ni][r] + b2v[ny][ni], 0.f);
                    pu += h * wav[ny][ni];
                    pw += h * wbv[ny][ni];
                }
            pu += __shfl_xor(pu, 1); pu += __shfl_xor(pu, 2);
            pu += __shfl_xor(pu, 4); pu += __shfl_xor(pu, 8);
            pw += __shfl_xor(pw, 1); pw += __shfl_xor(pw, 2);
            pw += __shfl_xor(pw, 4); pw += __shfl_xor(pw, 8);
            if ((lane & 15) == 0) {
                const int rl = wr + mi * 16 + ((lane >> 4) << 2) + r;
                uW[(wave & 3) * 64 + rl] = pu;
                wW[(wave & 3) * 64 + rl] = pw;
            }
        }
    __syncthreads();
    if (t < 64) {
        const int row = bm + t;
        if (row < NN) {
            u[row] = uW[t] + uW[64 + t] + uW[128 + t] + uW[192 + t];
            w[row] = wW[t] + wW[64 + t] + wW[128 + t] + wW[192 + t];
        }
    }
}

// ================= phase 5: P + edge outputs, tile bb (64 nodes) ==============
__device__ __forceinline__ void phase_out(int bb, int t, char* smem,
    const float* __restrict__ u, const float* __restrict__ w,
    const float* __restrict__ bl, float* __restrict__ out)
{
    const int v0 = bb * 64;
    const float inv17 = 1.0f / 17.0f;
    float* uS = (float*)smem;        // 88: u[v0-8 .. v0+79]
    float* wS = uS + 88;             // 72: w[v0 .. v0+71]
    float* PS = wS + 72;             // 72: P[v0 .. v0+71]
    if (t < 88) uS[t] = u[wrapN(v0 - 8 + t)];
    else if (t < 160) wS[t - 88] = w[wrapN(v0 + (t - 88))];
    __syncthreads();
    if (t < 72) {
        float s = uS[t + 8] + 16.0f * wS[t];
        #pragma unroll
        for (int o = 1; o <= 8; ++o)
            s += uS[t + 8 + o] + uS[t + 8 - o];
        PS[t] = s;
    }
    __syncthreads();
    const float blv = bl[0];
    #pragma unroll
    for (int rr = 0; rr < 2; ++rr) {
        const int q = t + rr * 512;
        const int qq = q & 511;
        const int p = qq >> 3, off = qq & 7;
        const int v = v0 + p;
        if (v >= NN) continue;
        if (q < 512) {
            out[v * 8 + off] = sigmoidf_((PS[p] + wS[p + 1 + off]) * inv17 + blv);
        } else {
            out[NK + v * 8 + off] = sigmoidf_((PS[p + 1 + off] + wS[p]) * inv17 + blv);
        }
    }
}

// ================= cooperative mega-kernel (256 blocks) =======================
__global__ __launch_bounds__(512, 2) void fused_all(
    const float* __restrict__ x,  const float* __restrict__ W1, const float* __restrict__ b1,
    const float* __restrict__ gamma1, const float* __restrict__ beta1,
    const float* __restrict__ W2, const float* __restrict__ b2,
    const float* __restrict__ Wl, const float* __restrict__ bl,
    float* __restrict__ out,
    ushort* __restrict__ xab, ushort* __restrict__ A, ushort* __restrict__ g,
    ushort* __restrict__ W1t, ushort* __restrict__ W2t,
    float* __restrict__ part, float* __restrict__ part2, float* __restrict__ ss,
    float* __restrict__ u, float* __restrict__ w)
{
    cg::grid_group grid = cg::this_grid();
    __shared__ alignas(16) char smem[40960];
    const int b = blockIdx.x, t = threadIdx.x;

    if (b < 127) phase_prep(b, t, x, W1, W2, W1t, W2t, xab);
    grid.sync();
    for (int bb = b; bb < NT1; bb += CNB) {
        phase_gemm1(bb, t, smem, xab, W1t, b1, A, part);
        __syncthreads();
    }
    grid.sync();
    if (b < 32) phase_bnred(b, t, part, part2);
    grid.sync();
    if (b == 0) phase_bnfin(t, smem, part2, gamma1, beta1, ss);
    grid.sync();
    if (b < 157) phase_mid(b, t, A, ss, g);
    grid.sync();
    for (int bb = b; bb < NT1; bb += CNB) {
        phase_gemm2(bb, t, smem, g, W2t, b2, Wl, u, w);
        __syncthreads();
    }
    grid.sync();
    for (int bb = b; bb < NT1; bb += CNB) {
        phase_out(bb, t, smem, u, w, bl, out);
        __syncthreads();
    }
}

// ================= fallback wrappers (plain launches) =========================
__global__ __launch_bounds__(512, 2) void k_prep(const float* x, const float* W1,
    const float* W2, ushort* W1t, ushort* W2t, ushort* xab, unsigned* cnt)
{
    if (blockIdx.x == 0 && threadIdx.x == 0) *cnt = 0u;
    phase_prep(blockIdx.x, threadIdx.x, x, W1, W2, W1t, W2t, xab);
}

__global__ __launch_bounds__(512, 2) void k_gemm1(const ushort* xab, const ushort* W1t,
    const float* b1, ushort* A, float* part)
{
    __shared__ alignas(16) char smem[40960];
    phase_gemm1(blockIdx.x, threadIdx.x, smem, xab, W1t, b1, A, part);
}

__global__ __launch_bounds__(512) void k_bncomb(const float* part, float* part2,
    const float* gamma, const float* beta, float* ss, unsigned* cnt)
{
    __shared__ alignas(16) char smem[2048];
    const int b = blockIdx.x, t = threadIdx.x;
    phase_bnred(b, t, part, part2);
    __threadfence();
    __syncthreads();
    __shared__ unsigned lastf;
    if (t == 0) lastf = (atomicAdd(cnt, 1u) == 31u) ? 1u : 0u;
    __syncthreads();
    if (!lastf) return;
    if (t == 0) *cnt = 0u;
    __threadfence();
    phase_bnfin(t, smem, part2, gamma, beta, ss);
}

__global__ __launch_bounds__(512, 2) void k_mid(const ushort* A, const float* ss, ushort* g)
{
    phase_mid(blockIdx.x, threadIdx.x, A, ss, g);
}

__global__ __launch_bounds__(512, 2) void k_gemm2(const ushort* g, const ushort* W2t,
    const float* b2, const float* Wl, float* u, float* w)
{
    __shared__ alignas(16) char smem[40960];
    phase_gemm2(blockIdx.x, threadIdx.x, smem, g, W2t, b2, Wl, u, w);
}

__global__ __launch_bounds__(512, 2) void k_out(const float* u, const float* w,
    const float* bl, float* out)
{
    __shared__ alignas(16) char smem[1024];
    phase_out(blockIdx.x, threadIdx.x, smem, u, w, bl, out);
}

// ---------------- launch ----------------
extern "C" void kernel_launch(void* const* d_in, const int* in_sizes, int n_in,
                              void* d_out, int out_size, void* d_ws, size_t ws_size,
                              hipStream_t stream)
{
    const float* x      = (const float*)d_in[0];
    const float* W1     = (const float*)d_in[1];
    const float* b1     = (const float*)d_in[2];
    const float* gamma1 = (const float*)d_in[3];
    const float* beta1  = (const float*)d_in[4];
    const float* W2     = (const float*)d_in[5];
    const float* b2     = (const float*)d_in[6];
    const float* Wl     = (const float*)d_in[7];
    const float* bl     = (const float*)d_in[8];
    float* out = (float*)d_out;

    float*    part  = (float*)d_ws;                  // [313,512]
    float*    part2 = part + 313 * 512;              // [32,512]
    float*    ss    = part2 + 32 * 512;              // [512]
    unsigned* cnt   = (unsigned*)(ss + 512);         // [4]
    float*    u     = (float*)(cnt + 4);             // [NN]
    float*    w     = u + NN;                        // [NN]
    ushort*   xab   = (ushort*)(w + NN);             // [NN,128] bf16
    ushort*   A     = xab + (size_t)NN * 128;        // [NN,256] bf16
    ushort*   g     = A + (size_t)NN * 256;          // [NN,256] bf16
    ushort*   W1t   = g + (size_t)NN * 256;          // [256,128]
    ushort*   W2t   = W1t + 256 * 128;               // [256,256]

    int coop = 0, dev = 0;
    (void)hipGetDevice(&dev);
    (void)hipDeviceGetAttribute(&coop, hipDeviceAttributeCooperativeLaunch, dev);

    hipError_t err = hipErrorUnknown;
    if (coop) {
        void* args[] = { &x, &W1, &b1, &gamma1, &beta1, &W2, &b2, &Wl, &bl, &out,
                         &xab, &A, &g, &W1t, &W2t, &part, &part2, &ss, &u, &w };
        err = hipLaunchCooperativeKernel((void*)fused_all, dim3(CNB), dim3(512),
                                         args, 0, stream);
    }
    if (err != hipSuccess) {
        (void)hipGetLastError();   // clear error state
        k_prep <<<127, 512, 0, stream>>>(x, W1, W2, W1t, W2t, xab, cnt);
        k_gemm1<<<NT1, 512, 0, stream>>>(xab, W1t, b1, A, part);
        k_bncomb<<<32, 512, 0, stream>>>(part, part2, gamma1, beta1, ss, cnt);
        k_mid  <<<157, 512, 0, stream>>>(A, ss, g);
        k_gemm2<<<NT1, 512, 0, stream>>>(g, W2t, b2, Wl, u, w);
        k_out  <<<NT1, 512, 0, stream>>>(u, w, bl, out);
    }
}

// Round 10
// 60.044 us; speedup vs baseline: 3.9120x; 3.9120x over previous
//
#include <hip/hip_runtime.h>
#include <hip/hip_bf16.h>
#include <math.h>

#define NN    20000
#define NK    160000          // NN*8
#define NEDGE 320000
#define HID   256
#define INFEAT 128
#define EPSF  1e-5f
#define NT1   313             // 64-row tiles

typedef __bf16  bf16x8 __attribute__((ext_vector_type(8)));
typedef float   f32x4  __attribute__((ext_vector_type(4)));
typedef ushort  u16x8  __attribute__((ext_vector_type(8)));

__device__ __forceinline__ float sigmoidf_(float x) { return 1.0f / (1.0f + expf(-x)); }

__device__ __forceinline__ ushort f2bf(float f) {
    __hip_bfloat16 h = __float2bfloat16(f);
    return __builtin_bit_cast(ushort, h);
}
__device__ __forceinline__ float bf2f(ushort u) {
    return __builtin_bit_cast(float, ((unsigned int)u) << 16);
}
__device__ __forceinline__ int wrapN(int v) {
    return (v < 0) ? v + NN : ((v >= NN) ? v - NN : v);
}

#define LDSP(p) ((__attribute__((address_space(3))) unsigned int*)(p))
#define GBLP(p) ((const __attribute__((address_space(1))) unsigned int*)(p))
#define GLD16(g, l) __builtin_amdgcn_global_load_lds(GBLP(g), LDSP(l), 16, 0, 0)

// ============ kernel 1: prep (xab=agg(x), W1t, W2t, zero asum), 128 blocks ============
__global__ __launch_bounds__(512, 2) void k_prep(const float* __restrict__ x,
    const float* __restrict__ W1, const float* __restrict__ W2,
    ushort* __restrict__ W1t, ushort* __restrict__ W2t,
    ushort* __restrict__ xab, float* __restrict__ asum)
{
    const int b = blockIdx.x, t = threadIdx.x;
    const float inv17 = 1.0f / 17.0f;
    if (b < 79) {
        const int item = b * 512 + t;
        if (item < 40000) {
            const int strip = item >> 4, fg = item & 15;
            const int f0 = fg * 8;
            const int vstart = strip * 8;
            float S[8] = {};
            #pragma unroll
            for (int o = -8; o <= 8; ++o) {
                const float* r = x + (size_t)wrapN(vstart + o) * INFEAT + f0;
                const float4 a = *reinterpret_cast<const float4*>(r);
                const float4 c = *reinterpret_cast<const float4*>(r + 4);
                S[0] += a.x; S[1] += a.y; S[2] += a.z; S[3] += a.w;
                S[4] += c.x; S[5] += c.y; S[6] += c.z; S[7] += c.w;
            }
            for (int i = 0; i < 8; ++i) {
                const int v = vstart + i;
                const float* ra = x + (size_t)wrapN(v + 9) * INFEAT + f0;
                const float* rs = x + (size_t)wrapN(v - 8) * INFEAT + f0;
                const float4 a0 = *reinterpret_cast<const float4*>(ra);
                const float4 a1 = *reinterpret_cast<const float4*>(ra + 4);
                const float4 s0 = *reinterpret_cast<const float4*>(rs);
                const float4 s1 = *reinterpret_cast<const float4*>(rs + 4);
                u16x8 o;
                #pragma unroll
                for (int j = 0; j < 8; ++j) o[j] = f2bf(S[j] * inv17);
                *reinterpret_cast<u16x8*>(xab + (size_t)v * INFEAT + f0) = o;
                S[0] += a0.x - s0.x; S[1] += a0.y - s0.y; S[2] += a0.z - s0.z; S[3] += a0.w - s0.w;
                S[4] += a1.x - s1.x; S[5] += a1.y - s1.y; S[6] += a1.z - s1.z; S[7] += a1.w - s1.w;
            }
        }
    } else if (b < 95) {
        const int e = ((b - 79) * 512 + t) * 4;     // W1t: 32768 elements
        ushort4 o;
        #pragma unroll
        for (int j = 0; j < 4; ++j) {
            const int ee = e + j;
            const int n = ee >> 7, k = ee & 127;    // W1t[n][k] = W1[k][n]
            ((ushort*)&o)[j] = f2bf(W1[k * 256 + n]);
        }
        *reinterpret_cast<ushort4*>(W1t + e) = o;
    } else if (b < 127) {
        const int e = ((b - 95) * 512 + t) * 4;     // W2t: 65536 elements
        ushort4 o;
        #pragma unroll
        for (int j = 0; j < 4; ++j) {
            const int ee = e + j;
            const int n = ee >> 8, k = ee & 255;    // W2t[n][k] = W2[k][n]
            ((ushort*)&o)[j] = f2bf(W2[k * 256 + n]);
        }
        *reinterpret_cast<ushort4*>(W2t + e) = o;
    } else {
        asum[t]       = 0.f;
        asum[512 + t] = 0.f;
    }
}

// ============ kernel 2: A = xab @ W1 + b1; BN partials -> atomicAdd(asum) ============
// 313 blocks x 512 threads; tile 64(M) x 256(N), BK=64, XOR-swizzled LDS.
__global__ __launch_bounds__(512, 2) void k_gemm1(const ushort* __restrict__ xab,
    const ushort* __restrict__ W1t, const float* __restrict__ b1,
    ushort* __restrict__ A, float* __restrict__ asum)
{
    __shared__ alignas(16) char smem[40960];
    char* As = smem;
    char* Bs = smem + 8192;
    const int t = threadIdx.x;
    const int wave = t >> 6, lane = t & 63;
    const int wr = (wave >> 2) * 32;
    const int wc = (wave & 3) * 32;
    const int bm = blockIdx.x * 64;
    f32x4 acc[2][2][2] = {};   // [ny][mi][ni]

    #pragma unroll
    for (int kt = 0; kt < 2; ++kt) {
        const int k0 = kt * 64;
        {   // stage A: 64x64 bf16
            const int c = wave * 64 + lane;
            const int row = c >> 3;
            const int lk = (c & 7) ^ (row & 7);
            int rg = bm + row; if (rg >= NN) rg = NN - 1;
            GLD16(xab + (size_t)rg * INFEAT + k0 + lk * 8, As + wave * 1024);
        }
        #pragma unroll
        for (int it = 0; it < 4; ++it) {   // stage B: 256x64
            const int cb = (it * 8 + wave) * 64 + lane;
            const int row = cb >> 3;
            const int lk = (cb & 7) ^ (row & 7);
            GLD16(W1t + (size_t)row * INFEAT + k0 + lk * 8, Bs + (it * 8 + wave) * 1024);
        }
        __syncthreads();
        #pragma unroll
        for (int kk = 0; kk < 2; ++kk) {
            const int klog = kk * 64 + ((lane >> 4) << 4);
            bf16x8 af[2];
            #pragma unroll
            for (int mi = 0; mi < 2; ++mi) {
                const int row = wr + mi * 16 + (lane & 15);
                af[mi] = *reinterpret_cast<const bf16x8*>(As + row * 128 + (klog ^ ((row & 7) << 4)));
            }
            #pragma unroll
            for (int ny = 0; ny < 2; ++ny)
                #pragma unroll
                for (int ni = 0; ni < 2; ++ni) {
                    const int row = ny * 128 + wc + ni * 16 + (lane & 15);
                    const bf16x8 bv = *reinterpret_cast<const bf16x8*>(Bs + row * 128 + (klog ^ ((row & 7) << 4)));
                    #pragma unroll
                    for (int mi = 0; mi < 2; ++mi)
                        acc[ny][mi][ni] = __builtin_amdgcn_mfma_f32_16x16x32_bf16(af[mi], bv, acc[ny][mi][ni], 0, 0, 0);
                }
        }
        __syncthreads();
    }

    // epilogue: bias, store A (bf16), BN partials -> global atomic accumulation
    float* sS  = (float*)smem;            // [8][64]
    float* s2S = (float*)(smem + 2048);   // [8][64]
    #pragma unroll
    for (int ny = 0; ny < 2; ++ny)
        #pragma unroll
        for (int ni = 0; ni < 2; ++ni) {
            const int colL = ny * 128 + wc + ni * 16 + (lane & 15);
            const float bv = b1[colL];
            float sv = 0.f, s2v = 0.f;
            #pragma unroll
            for (int mi = 0; mi < 2; ++mi)
                #pragma unroll
                for (int r = 0; r < 4; ++r) {
                    const int row = bm + wr + mi * 16 + ((lane >> 4) << 2) + r;
                    if (row < NN) {
                        const float val = acc[ny][mi][ni][r] + bv;
                        A[(size_t)row * 256 + colL] = f2bf(val);
                        sv += val; s2v += val * val;
                    }
                }
            sv  += __shfl_xor(sv, 16);  sv  += __shfl_xor(sv, 32);
            s2v += __shfl_xor(s2v, 16); s2v += __shfl_xor(s2v, 32);
            if (lane < 16) {
                sS [wave * 64 + ny * 32 + ni * 16 + lane] = sv;
                s2S[wave * 64 + ny * 32 + ni * 16 + lane] = s2v;
            }
        }
    __syncthreads();
    if (t < 256) {
        const int col = t;
        const int idx = (col >> 7) * 32 + ((col >> 4) & 1) * 16 + (col & 15);
        const int wcx = (col & 127) >> 5;
        atomicAdd(&asum[col],       sS [wcx * 64 + idx] + sS [(wcx + 4) * 64 + idx]);
        atomicAdd(&asum[512 + col], s2S[wcx * 64 + idx] + s2S[(wcx + 4) * 64 + idx]);
    }
}

// ===== kernel 3: h2 = relu( agg(relu(bn(A))) @ W2 + b2 ), dots -> u,w =====
// BN scale/shift computed per-block from asum; mid (agg2) fused into A-staging.
__global__ __launch_bounds__(512, 2) void k_gemm2(const ushort* __restrict__ A,
    const ushort* __restrict__ W2t, const float* __restrict__ gamma,
    const float* __restrict__ beta, const float* __restrict__ b2,
    const float* __restrict__ Wl, const float* __restrict__ asum,
    float* __restrict__ u, float* __restrict__ w)
{
    __shared__ alignas(16) char smem[53248];
    char* As   = smem;                    // 8192:  64 x 128B (swizzled bf16)
    char* Bs   = smem + 8192;             // 32768: 256 x 128B (swizzled bf16)
    char* xraw = smem + 40960;            // 10240: 80 x 128B (linear bf16)
    float* ssS = (float*)(smem + 51200);  // 2048:  sc[256] | sh[256]

    const int t = threadIdx.x;
    const int wave = t >> 6, lane = t & 63;
    const int wr = (wave >> 2) * 32;
    const int wc = (wave & 3) * 32;
    const int bm = blockIdx.x * 64;
    const float inv17 = 1.0f / 17.0f;

    if (t < 256) {
        const float invn = 1.0f / (float)NN;
        const float mu  = asum[t] * invn;
        const float var = asum[512 + t] * invn - mu * mu;
        const float sc  = gamma[t] * rsqrtf(var + EPSF);
        ssS[t]       = sc;
        ssS[256 + t] = beta[t] - mu * sc;
    }
    __syncthreads();

    f32x4 acc[2][2][2] = {};

    #pragma unroll
    for (int kt = 0; kt < 4; ++kt) {
        const int k0 = kt * 64;
        {   // stage raw A rows [bm-8, bm+72), cols [k0,k0+64): 640 chunks, linear
            const int c = wave * 64 + lane;
            const int row = c >> 3;
            const int rg = wrapN(bm - 8 + row);
            GLD16(A + (size_t)rg * 256 + k0 + (c & 7) * 8, xraw + wave * 1024);
            if (wave < 2) {
                const int c1 = 512 + wave * 64 + lane;
                const int row1 = c1 >> 3;
                const int rg1 = wrapN(bm - 8 + row1);
                GLD16(A + (size_t)rg1 * 256 + k0 + (c1 & 7) * 8, xraw + (8 + wave) * 1024);
            }
        }
        #pragma unroll
        for (int it = 0; it < 4; ++it) {   // stage B: 256x64, swizzled source
            const int cb = (it * 8 + wave) * 64 + lane;
            const int row = cb >> 3;
            const int lk = (cb & 7) ^ (row & 7);
            GLD16(W2t + (size_t)row * 256 + k0 + lk * 8, Bs + (it * 8 + wave) * 1024);
        }
        __syncthreads();
        {   // build As[64][64] = (1/17) * sum_{i=0..16} relu(bn(xraw[row+i]))
            const int row = t >> 3, c8 = t & 7;
            const int fb = k0 + c8 * 8;
            float scv[8], shv[8];
            #pragma unroll
            for (int j = 0; j < 8; ++j) { scv[j] = ssS[fb + j]; shv[j] = ssS[256 + fb + j]; }
            float S[8] = {};
            #pragma unroll
            for (int i = 0; i < 17; ++i) {
                const u16x8 hv = *reinterpret_cast<const u16x8*>(xraw + (row + i) * 128 + c8 * 16);
                #pragma unroll
                for (int j = 0; j < 8; ++j)
                    S[j] += fmaxf(bf2f(hv[j]) * scv[j] + shv[j], 0.f);
            }
            u16x8 o;
            #pragma unroll
            for (int j = 0; j < 8; ++j) o[j] = f2bf(S[j] * inv17);
            *reinterpret_cast<u16x8*>(As + row * 128 + ((c8 ^ (row & 7)) * 16)) = o;
        }
        __syncthreads();
        #pragma unroll
        for (int kk = 0; kk < 2; ++kk) {
            const int klog = kk * 64 + ((lane >> 4) << 4);
            bf16x8 af[2];
            #pragma unroll
            for (int mi = 0; mi < 2; ++mi) {
                const int row = wr + mi * 16 + (lane & 15);
                af[mi] = *reinterpret_cast<const bf16x8*>(As + row * 128 + (klog ^ ((row & 7) << 4)));
            }
            #pragma unroll
            for (int ny = 0; ny < 2; ++ny)
                #pragma unroll
                for (int ni = 0; ni < 2; ++ni) {
                    const int row = ny * 128 + wc + ni * 16 + (lane & 15);
                    const bf16x8 bv = *reinterpret_cast<const bf16x8*>(Bs + row * 128 + (klog ^ ((row & 7) << 4)));
                    #pragma unroll
                    for (int mi = 0; mi < 2; ++mi)
                        acc[ny][mi][ni] = __builtin_amdgcn_mfma_f32_16x16x32_bf16(af[mi], bv, acc[ny][mi][ni], 0, 0, 0);
                }
        }
        __syncthreads();
    }

    // epilogue: relu + per-row dots with Wl -> u,w (full 256 cols in-block)
    float b2v[2][2], wav[2][2], wbv[2][2];
    #pragma unroll
    for (int ny = 0; ny < 2; ++ny)
        #pragma unroll
        for (int ni = 0; ni < 2; ++ni) {
            const int col = ny * 128 + wc + ni * 16 + (lane & 15);
            b2v[ny][ni] = b2[col];
            wav[ny][ni] = Wl[col];
            wbv[ny][ni] = Wl[256 + col];
        }
    float* uW = (float*)smem;            // [4][64]
    float* wW = (float*)(smem + 1024);   // [4][64]
    #pragma unroll
    for (int mi = 0; mi < 2; ++mi)
        #pragma unroll
        for (int r = 0; r < 4; ++r) {
            float pu = 0.f, pw = 0.f;
            #pragma unroll
            for (int ny = 0; ny < 2; ++ny)
                #pragma unroll
                for (int ni = 0; ni < 2; ++ni) {
                    const float h = fmaxf(acc[ny][mi][ni][r] + b2v[ny][ni], 0.f);
                    pu += h * wav[ny][ni];
                    pw += h * wbv[ny][ni];
                }
            pu += __shfl_xor(pu, 1); pu += __shfl_xor(pu, 2);
            pu += __shfl_xor(pu, 4); pu += __shfl_xor(pu, 8);
            pw += __shfl_xor(pw, 1); pw += __shfl_xor(pw, 2);
            pw += __shfl_xor(pw, 4); pw += __shfl_xor(pw, 8);
            if ((lane & 15) == 0) {
                const int rl = wr + mi * 16 + ((lane >> 4) << 2) + r;
                uW[(wave & 3) * 64 + rl] = pu;
                wW[(wave & 3) * 64 + rl] = pw;
            }
        }
    __syncthreads();
    if (t < 64) {
        const int row = bm + t;
        if (row < NN) {
            u[row] = uW[t] + uW[64 + t] + uW[128 + t] + uW[192 + t];
            w[row] = wW[t] + wW[64 + t] + wW[128 + t] + wW[192 + t];
        }
    }
}

// ============ kernel 4: P + edge outputs, 313 blocks x 512 (64 nodes each) ============
__global__ __launch_bounds__(512, 2) void k_out(const float* __restrict__ u,
    const float* __restrict__ w, const float* __restrict__ bl, float* __restrict__ out)
{
    const int bb = blockIdx.x, t = threadIdx.x;
    const int v0 = bb * 64;
    const float inv17 = 1.0f / 17.0f;
    __shared__ float uS[88];   // u[v0-8 .. v0+79]
    __shared__ float wS[72];   // w[v0 .. v0+71]
    __shared__ float PS[72];
    if (t < 88) uS[t] = u[wrapN(v0 - 8 + t)];
    else if (t < 160) wS[t - 88] = w[wrapN(v0 + (t - 88))];
    __syncthreads();
    if (t < 72) {
        float s = uS[t + 8] + 16.0f * wS[t];
        #pragma unroll
        for (int o = 1; o <= 8; ++o)
            s += uS[t + 8 + o] + uS[t + 8 - o];
        PS[t] = s;
    }
    __syncthreads();
    const float blv = bl[0];
    #pragma unroll
    for (int rr = 0; rr < 2; ++rr) {
        const int q = t + rr * 512;
        const int qq = q & 511;
        const int p = qq >> 3, off = qq & 7;
        const int v = v0 + p;
        if (v >= NN) continue;
        if (q < 512) {
            out[v * 8 + off] = sigmoidf_((PS[p] + wS[p + 1 + off]) * inv17 + blv);
        } else {
            out[NK + v * 8 + off] = sigmoidf_((PS[p + 1 + off] + wS[p]) * inv17 + blv);
        }
    }
}

// ---------------- launch ----------------
extern "C" void kernel_launch(void* const* d_in, const int* in_sizes, int n_in,
                              void* d_out, int out_size, void* d_ws, size_t ws_size,
                              hipStream_t stream)
{
    const float* x      = (const float*)d_in[0];
    const float* W1     = (const float*)d_in[1];
    const float* b1     = (const float*)d_in[2];
    const float* gamma1 = (const float*)d_in[3];
    const float* beta1  = (const float*)d_in[4];
    const float* W2     = (const float*)d_in[5];
    const float* b2     = (const float*)d_in[6];
    const float* Wl     = (const float*)d_in[7];
    const float* bl     = (const float*)d_in[8];
    float* out = (float*)d_out;

    float*    asum = (float*)d_ws;                   // [1024]
    float*    u    = asum + 1024;                    // [NN]
    float*    w    = u + NN;                         // [NN]
    ushort*   xab  = (ushort*)(w + NN);              // [NN,128] bf16
    ushort*   A    = xab + (size_t)NN * 128;         // [NN,256] bf16
    ushort*   W1t  = A + (size_t)NN * 256;           // [256,128]
    ushort*   W2t  = W1t + 256 * 128;                // [256,256]

    k_prep <<<128, 512, 0, stream>>>(x, W1, W2, W1t, W2t, xab, asum);
    k_gemm1<<<NT1, 512, 0, stream>>>(xab, W1t, b1, A, asum);
    k_gemm2<<<NT1, 512, 0, stream>>>(A, W2t, gamma1, beta1, b2, Wl, asum, u, w);
    k_out  <<<NT1, 512, 0, stream>>>(u, w, bl, out);
}

// Round 11
// 50.530 us; speedup vs baseline: 4.6486x; 1.1883x over previous
//
#include <hip/hip_runtime.h>
#include <hip/hip_bf16.h>
#include <math.h>

#define NN    20000
#define NK    160000          // NN*8
#define NEDGE 320000
#define HID   256
#define INFEAT 128
#define EPSF  1e-5f
#define NT1   313             // 64-row tiles

typedef __bf16  bf16x8 __attribute__((ext_vector_type(8)));
typedef float   f32x4  __attribute__((ext_vector_type(4)));
typedef ushort  u16x8  __attribute__((ext_vector_type(8)));

__device__ __forceinline__ float sigmoidf_(float x) { return 1.0f / (1.0f + expf(-x)); }

__device__ __forceinline__ ushort f2bf(float f) {
    __hip_bfloat16 h = __float2bfloat16(f);
    return __builtin_bit_cast(ushort, h);
}
__device__ __forceinline__ float bf2f(ushort u) {
    return __builtin_bit_cast(float, ((unsigned int)u) << 16);
}
__device__ __forceinline__ int wrapN(int v) {
    return (v < 0) ? v + NN : ((v >= NN) ? v - NN : v);
}

#define LDSP(p) ((__attribute__((address_space(3))) unsigned int*)(p))
#define GBLP(p) ((const __attribute__((address_space(1))) unsigned int*)(p))
#define GLD16(g, l) __builtin_amdgcn_global_load_lds(GBLP(g), LDSP(l), 16, 0, 0)

// ============ kernel 1: prep (W1t, W2t, zero asum), 49 blocks ============
__global__ __launch_bounds__(512, 2) void k_prep(const float* __restrict__ W1,
    const float* __restrict__ W2, ushort* __restrict__ W1t,
    ushort* __restrict__ W2t, float* __restrict__ asum)
{
    const int b = blockIdx.x, t = threadIdx.x;
    if (b < 16) {
        const int e = (b * 512 + t) * 4;            // W1t: 32768 elements
        ushort4 o;
        #pragma unroll
        for (int j = 0; j < 4; ++j) {
            const int ee = e + j;
            const int n = ee >> 7, k = ee & 127;    // W1t[n][k] = W1[k][n]
            ((ushort*)&o)[j] = f2bf(W1[k * 256 + n]);
        }
        *reinterpret_cast<ushort4*>(W1t + e) = o;
    } else if (b < 48) {
        const int e = ((b - 16) * 512 + t) * 4;     // W2t: 65536 elements
        ushort4 o;
        #pragma unroll
        for (int j = 0; j < 4; ++j) {
            const int ee = e + j;
            const int n = ee >> 8, k = ee & 255;    // W2t[n][k] = W2[k][n]
            ((ushort*)&o)[j] = f2bf(W2[k * 256 + n]);
        }
        *reinterpret_cast<ushort4*>(W2t + e) = o;
    } else {
        asum[t]       = 0.f;
        asum[512 + t] = 0.f;
    }
}

// ====== kernel 2: A = agg(x) @ W1 + b1 (agg fused in staging); BN partials -> asum ======
// 313 blocks x 512; tile 64(M) x 256(N), BK=64. xraw: 80 rows f32, 272B padded stride.
__global__ __launch_bounds__(512, 2) void k_fused1(const float* __restrict__ x,
    const ushort* __restrict__ W1t, const float* __restrict__ b1,
    ushort* __restrict__ A, float* __restrict__ asum)
{
    __shared__ alignas(16) char smem[21760 + 8192 + 32768];
    char* xr = smem;                    // 80 x 272B (f32, padded)
    char* As = smem + 21760;            // 64 x 128B (bf16, swizzled)
    char* Bs = smem + 21760 + 8192;     // 256 x 128B (bf16, swizzled)

    const int t = threadIdx.x;
    const int wave = t >> 6, lane = t & 63;
    const int wr = (wave >> 2) * 32;
    const int wc = (wave & 3) * 32;
    const int bm = blockIdx.x * 64;
    const float inv17 = 1.0f / 17.0f;
    f32x4 acc[2][2][2] = {};   // [ny][mi][ni]

    #pragma unroll
    for (int kt = 0; kt < 2; ++kt) {
        const int k0 = kt * 64;
        #pragma unroll
        for (int it = 0; it < 4; ++it) {   // stage B (async): 256x64 bf16, swizzled src
            const int cb = (it * 8 + wave) * 64 + lane;
            const int row = cb >> 3;
            const int lk = (cb & 7) ^ (row & 7);
            GLD16(W1t + (size_t)row * INFEAT + k0 + lk * 8, Bs + (it * 8 + wave) * 1024);
        }
        // reg-stage xraw: x rows [bm-8, bm+72) x 64 f32 cols, padded stride
        #pragma unroll
        for (int r3 = 0; r3 < 3; ++r3) {
            const int c = r3 * 512 + t;
            if (c < 1280) {
                const int row = c >> 4, cc = c & 15;
                const int rg = wrapN(bm - 8 + row);
                const float4 v = *reinterpret_cast<const float4*>(
                    x + (size_t)rg * INFEAT + k0 + cc * 4);
                *reinterpret_cast<float4*>(xr + row * 272 + cc * 16) = v;
            }
        }
        __syncthreads();
        {   // build As[row][64] = (1/17) * sum_{i=0..16} xraw[row+i]
            const int row = t >> 3, c8 = t & 7;
            float S[8] = {};
            #pragma unroll
            for (int i = 0; i < 17; ++i) {
                const float4 a = *reinterpret_cast<const float4*>(xr + (row + i) * 272 + c8 * 32);
                const float4 bq = *reinterpret_cast<const float4*>(xr + (row + i) * 272 + c8 * 32 + 16);
                S[0] += a.x;  S[1] += a.y;  S[2] += a.z;  S[3] += a.w;
                S[4] += bq.x; S[5] += bq.y; S[6] += bq.z; S[7] += bq.w;
            }
            u16x8 o;
            #pragma unroll
            for (int j = 0; j < 8; ++j) o[j] = f2bf(S[j] * inv17);
            *reinterpret_cast<u16x8*>(As + row * 128 + ((c8 ^ (row & 7)) * 16)) = o;
        }
        __syncthreads();
        #pragma unroll
        for (int kk = 0; kk < 2; ++kk) {
            const int klog = kk * 64 + ((lane >> 4) << 4);
            bf16x8 af[2];
            #pragma unroll
            for (int mi = 0; mi < 2; ++mi) {
                const int row = wr + mi * 16 + (lane & 15);
                af[mi] = *reinterpret_cast<const bf16x8*>(As + row * 128 + (klog ^ ((row & 7) << 4)));
            }
            #pragma unroll
            for (int ny = 0; ny < 2; ++ny)
                #pragma unroll
                for (int ni = 0; ni < 2; ++ni) {
                    const int row = ny * 128 + wc + ni * 16 + (lane & 15);
                    const bf16x8 bv = *reinterpret_cast<const bf16x8*>(Bs + row * 128 + (klog ^ ((row & 7) << 4)));
                    #pragma unroll
                    for (int mi = 0; mi < 2; ++mi)
                        acc[ny][mi][ni] = __builtin_amdgcn_mfma_f32_16x16x32_bf16(af[mi], bv, acc[ny][mi][ni], 0, 0, 0);
                }
        }
        __syncthreads();
    }

    // epilogue: bias, store A (bf16), BN partials -> global atomic accumulation
    float* sS  = (float*)smem;            // [8][64]
    float* s2S = (float*)(smem + 2048);   // [8][64]
    #pragma unroll
    for (int ny = 0; ny < 2; ++ny)
        #pragma unroll
        for (int ni = 0; ni < 2; ++ni) {
            const int colL = ny * 128 + wc + ni * 16 + (lane & 15);
            const float bv = b1[colL];
            float sv = 0.f, s2v = 0.f;
            #pragma unroll
            for (int mi = 0; mi < 2; ++mi)
                #pragma unroll
                for (int r = 0; r < 4; ++r) {
                    const int row = bm + wr + mi * 16 + ((lane >> 4) << 2) + r;
                    if (row < NN) {
                        const float val = acc[ny][mi][ni][r] + bv;
                        A[(size_t)row * 256 + colL] = f2bf(val);
                        sv += val; s2v += val * val;
                    }
                }
            sv  += __shfl_xor(sv, 16);  sv  += __shfl_xor(sv, 32);
            s2v += __shfl_xor(s2v, 16); s2v += __shfl_xor(s2v, 32);
            if (lane < 16) {
                sS [wave * 64 + ny * 32 + ni * 16 + lane] = sv;
                s2S[wave * 64 + ny * 32 + ni * 16 + lane] = s2v;
            }
        }
    __syncthreads();
    if (t < 256) {
        const int col = t;
        const int idx = (col >> 7) * 32 + ((col >> 4) & 1) * 16 + (col & 15);
        const int wcx = (col & 127) >> 5;
        atomicAdd(&asum[col],       sS [wcx * 64 + idx] + sS [(wcx + 4) * 64 + idx]);
        atomicAdd(&asum[512 + col], s2S[wcx * 64 + idx] + s2S[(wcx + 4) * 64 + idx]);
    }
}

// ===== kernel 3: h2 = relu( agg(relu(bn(A))) @ W2 + b2 ), dots -> u,w =====
// bn+relu applied once during reg-staging (bf16 out, 160B padded stride).
__global__ __launch_bounds__(512, 2) void k_fused2(const ushort* __restrict__ A,
    const ushort* __restrict__ W2t, const float* __restrict__ gamma,
    const float* __restrict__ beta, const float* __restrict__ b2,
    const float* __restrict__ Wl, const float* __restrict__ asum,
    float* __restrict__ u, float* __restrict__ w)
{
    __shared__ alignas(16) char smem[12800 + 8192 + 32768 + 2048];
    char* xr   = smem;                            // 80 x 160B (bf16 bnrelu'd, padded)
    char* As   = smem + 12800;                    // 64 x 128B swizzled
    char* Bs   = smem + 12800 + 8192;             // 256 x 128B swizzled
    float* ssS = (float*)(smem + 12800 + 8192 + 32768);  // sc[256] | sh[256]

    const int t = threadIdx.x;
    const int wave = t >> 6, lane = t & 63;
    const int wr = (wave >> 2) * 32;
    const int wc = (wave & 3) * 32;
    const int bm = blockIdx.x * 64;
    const float inv17 = 1.0f / 17.0f;

    if (t < 256) {
        const float invn = 1.0f / (float)NN;
        const float mu  = asum[t] * invn;
        const float var = asum[512 + t] * invn - mu * mu;
        const float sc  = gamma[t] * rsqrtf(var + EPSF);
        ssS[t]       = sc;
        ssS[256 + t] = beta[t] - mu * sc;
    }
    __syncthreads();

    f32x4 acc[2][2][2] = {};

    #pragma unroll
    for (int kt = 0; kt < 4; ++kt) {
        const int k0 = kt * 64;
        #pragma unroll
        for (int it = 0; it < 4; ++it) {   // stage B (async): 256x64, swizzled src
            const int cb = (it * 8 + wave) * 64 + lane;
            const int row = cb >> 3;
            const int lk = (cb & 7) ^ (row & 7);
            GLD16(W2t + (size_t)row * 256 + k0 + lk * 8, Bs + (it * 8 + wave) * 1024);
        }
        // reg-stage xr = bnrelu(A rows [bm-8, bm+72), cols [k0,k0+64)): 640 chunks
        #pragma unroll
        for (int r2 = 0; r2 < 2; ++r2) {
            const int c = r2 * 512 + t;
            if (c < 640) {
                const int row = c >> 3, c8 = c & 7;
                const int rg = wrapN(bm - 8 + row);
                const int fb = k0 + c8 * 8;
                const u16x8 a = *reinterpret_cast<const u16x8*>(A + (size_t)rg * 256 + fb);
                const float4 sc0 = *reinterpret_cast<const float4*>(ssS + fb);
                const float4 sc1 = *reinterpret_cast<const float4*>(ssS + fb + 4);
                const float4 sh0 = *reinterpret_cast<const float4*>(ssS + 256 + fb);
                const float4 sh1 = *reinterpret_cast<const float4*>(ssS + 256 + fb + 4);
                u16x8 p;
                p[0] = f2bf(fmaxf(bf2f(a[0]) * sc0.x + sh0.x, 0.f));
                p[1] = f2bf(fmaxf(bf2f(a[1]) * sc0.y + sh0.y, 0.f));
                p[2] = f2bf(fmaxf(bf2f(a[2]) * sc0.z + sh0.z, 0.f));
                p[3] = f2bf(fmaxf(bf2f(a[3]) * sc0.w + sh0.w, 0.f));
                p[4] = f2bf(fmaxf(bf2f(a[4]) * sc1.x + sh1.x, 0.f));
                p[5] = f2bf(fmaxf(bf2f(a[5]) * sc1.y + sh1.y, 0.f));
                p[6] = f2bf(fmaxf(bf2f(a[6]) * sc1.z + sh1.z, 0.f));
                p[7] = f2bf(fmaxf(bf2f(a[7]) * sc1.w + sh1.w, 0.f));
                *reinterpret_cast<u16x8*>(xr + row * 160 + c8 * 16) = p;
            }
        }
        __syncthreads();
        {   // build As[row][64] = (1/17) * sum_{i=0..16} xr[row+i]
            const int row = t >> 3, c8 = t & 7;
            float S[8] = {};
            #pragma unroll
            for (int i = 0; i < 17; ++i) {
                const u16x8 h = *reinterpret_cast<const u16x8*>(xr + (row + i) * 160 + c8 * 16);
                #pragma unroll
                for (int j = 0; j < 8; ++j) S[j] += bf2f(h[j]);
            }
            u16x8 o;
            #pragma unroll
            for (int j = 0; j < 8; ++j) o[j] = f2bf(S[j] * inv17);
            *reinterpret_cast<u16x8*>(As + row * 128 + ((c8 ^ (row & 7)) * 16)) = o;
        }
        __syncthreads();
        #pragma unroll
        for (int kk = 0; kk < 2; ++kk) {
            const int klog = kk * 64 + ((lane >> 4) << 4);
            bf16x8 af[2];
            #pragma unroll
            for (int mi = 0; mi < 2; ++mi) {
                const int row = wr + mi * 16 + (lane & 15);
                af[mi] = *reinterpret_cast<const bf16x8*>(As + row * 128 + (klog ^ ((row & 7) << 4)));
            }
            #pragma unroll
            for (int ny = 0; ny < 2; ++ny)
                #pragma unroll
                for (int ni = 0; ni < 2; ++ni) {
                    const int row = ny * 128 + wc + ni * 16 + (lane & 15);
                    const bf16x8 bv = *reinterpret_cast<const bf16x8*>(Bs + row * 128 + (klog ^ ((row & 7) << 4)));
                    #pragma unroll
                    for (int mi = 0; mi < 2; ++mi)
                        acc[ny][mi][ni] = __builtin_amdgcn_mfma_f32_16x16x32_bf16(af[mi], bv, acc[ny][mi][ni], 0, 0, 0);
                }
        }
        __syncthreads();
    }

    // epilogue: relu + per-row dots with Wl -> u,w (full 256 cols in-block)
    float b2v[2][2], wav[2][2], wbv[2][2];
    #pragma unroll
    for (int ny = 0; ny < 2; ++ny)
        #pragma unroll
        for (int ni = 0; ni < 2; ++ni) {
            const int col = ny * 128 + wc + ni * 16 + (lane & 15);
            b2v[ny][ni] = b2[col];
            wav[ny][ni] = Wl[col];
            wbv[ny][ni] = Wl[256 + col];
        }
    float* uW = (float*)smem;            // [4][64]
    float* wW = (float*)(smem + 1024);   // [4][64]
    #pragma unroll
    for (int mi = 0; mi < 2; ++mi)
        #pragma unroll
        for (int r = 0; r < 4; ++r) {
            float pu = 0.f, pw = 0.f;
            #pragma unroll
            for (int ny = 0; ny < 2; ++ny)
                #pragma unroll
                for (int ni = 0; ni < 2; ++ni) {
                    const float h = fmaxf(acc[ny][mi][ni][r] + b2v[ny][ni], 0.f);
                    pu += h * wav[ny][ni];
                    pw += h * wbv[ny][ni];
                }
            pu += __shfl_xor(pu, 1); pu += __shfl_xor(pu, 2);
            pu += __shfl_xor(pu, 4); pu += __shfl_xor(pu, 8);
            pw += __shfl_xor(pw, 1); pw += __shfl_xor(pw, 2);
            pw += __shfl_xor(pw, 4); pw += __shfl_xor(pw, 8);
            if ((lane & 15) == 0) {
                const int rl = wr + mi * 16 + ((lane >> 4) << 2) + r;
                uW[(wave & 3) * 64 + rl] = pu;
                wW[(wave & 3) * 64 + rl] = pw;
            }
        }
    __syncthreads();
    if (t < 64) {
        const int row = bm + t;
        if (row < NN) {
            u[row] = uW[t] + uW[64 + t] + uW[128 + t] + uW[192 + t];
            w[row] = wW[t] + wW[64 + t] + wW[128 + t] + wW[192 + t];
        }
    }
}

// ============ kernel 4: P + edge outputs, 313 blocks x 512 (64 nodes each) ============
__global__ __launch_bounds__(512, 2) void k_out(const float* __restrict__ u,
    const float* __restrict__ w, const float* __restrict__ bl, float* __restrict__ out)
{
    const int bb = blockIdx.x, t = threadIdx.x;
    const int v0 = bb * 64;
    const float inv17 = 1.0f / 17.0f;
    __shared__ float uS[88];   // u[v0-8 .. v0+79]
    __shared__ float wS[72];   // w[v0 .. v0+71]
    __shared__ float PS[72];
    if (t < 88) uS[t] = u[wrapN(v0 - 8 + t)];
    else if (t < 160) wS[t - 88] = w[wrapN(v0 + (t - 88))];
    __syncthreads();
    if (t < 72) {
        float s = uS[t + 8] + 16.0f * wS[t];
        #pragma unroll
        for (int o = 1; o <= 8; ++o)
            s += uS[t + 8 + o] + uS[t + 8 - o];
        PS[t] = s;
    }
    __syncthreads();
    const float blv = bl[0];
    #pragma unroll
    for (int rr = 0; rr < 2; ++rr) {
        const int q = t + rr * 512;
        const int qq = q & 511;
        const int p = qq >> 3, off = qq & 7;
        const int v = v0 + p;
        if (v >= NN) continue;
        if (q < 512) {
            out[v * 8 + off] = sigmoidf_((PS[p] + wS[p + 1 + off]) * inv17 + blv);
        } else {
            out[NK + v * 8 + off] = sigmoidf_((PS[p + 1 + off] + wS[p]) * inv17 + blv);
        }
    }
}

// ---------------- launch ----------------
extern "C" void kernel_launch(void* const* d_in, const int* in_sizes, int n_in,
                              void* d_out, int out_size, void* d_ws, size_t ws_size,
                              hipStream_t stream)
{
    const float* x      = (const float*)d_in[0];
    const float* W1     = (const float*)d_in[1];
    const float* b1     = (const float*)d_in[2];
    const float* gamma1 = (const float*)d_in[3];
    const float* beta1  = (const float*)d_in[4];
    const float* W2     = (const float*)d_in[5];
    const float* b2     = (const float*)d_in[6];
    const float* Wl     = (const float*)d_in[7];
    const float* bl     = (const float*)d_in[8];
    float* out = (float*)d_out;

    float*    asum = (float*)d_ws;                   // [1024]
    float*    u    = asum + 1024;                    // [NN]
    float*    w    = u + NN;                         // [NN]
    ushort*   A    = (ushort*)(w + NN);              // [NN,256] bf16
    ushort*   W1t  = A + (size_t)NN * 256;           // [256,128]
    ushort*   W2t  = W1t + 256 * 128;                // [256,256]

    k_prep  <<<49,  512, 0, stream>>>(W1, W2, W1t, W2t, asum);
    k_fused1<<<NT1, 512, 0, stream>>>(x, W1t, b1, A, asum);
    k_fused2<<<NT1, 512, 0, stream>>>(A, W2t, gamma1, beta1, b2, Wl, asum, u, w);
    k_out   <<<NT1, 512, 0, stream>>>(u, w, bl, out);
}

// Round 12
// 49.790 us; speedup vs baseline: 4.7177x; 1.0149x over previous
//
#include <hip/hip_runtime.h>
#include <hip/hip_bf16.h>
#include <math.h>

#define NN    20000
#define NK    160000          // NN*8
#define NEDGE 320000
#define HID   256
#define INFEAT 128
#define EPSF  1e-5f
#define NT1   313             // 64-row tiles (fused1 / out)
#define NT2   157             // 128-row tiles (fused2)

typedef __bf16  bf16x8 __attribute__((ext_vector_type(8)));
typedef float   f32x4  __attribute__((ext_vector_type(4)));
typedef ushort  u16x8  __attribute__((ext_vector_type(8)));

__device__ __forceinline__ float sigmoidf_(float x) { return 1.0f / (1.0f + expf(-x)); }

__device__ __forceinline__ ushort f2bf(float f) {
    __hip_bfloat16 h = __float2bfloat16(f);
    return __builtin_bit_cast(ushort, h);
}
__device__ __forceinline__ float bf2f(ushort u) {
    return __builtin_bit_cast(float, ((unsigned int)u) << 16);
}
__device__ __forceinline__ int wrapN(int v) {
    return (v < 0) ? v + NN : ((v >= NN) ? v - NN : v);
}

#define LDSP(p) ((__attribute__((address_space(3))) unsigned int*)(p))
#define GBLP(p) ((const __attribute__((address_space(1))) unsigned int*)(p))
#define GLD16(g, l) __builtin_amdgcn_global_load_lds(GBLP(g), LDSP(l), 16, 0, 0)

// ============ kernel 1: prep (W1t, W2t, zero asum), 49 blocks ============
__global__ __launch_bounds__(512, 2) void k_prep(const float* __restrict__ W1,
    const float* __restrict__ W2, ushort* __restrict__ W1t,
    ushort* __restrict__ W2t, float* __restrict__ asum)
{
    const int b = blockIdx.x, t = threadIdx.x;
    if (b < 16) {
        const int e = (b * 512 + t) * 4;            // W1t: 32768 elements
        ushort4 o;
        #pragma unroll
        for (int j = 0; j < 4; ++j) {
            const int ee = e + j;
            const int n = ee >> 7, k = ee & 127;    // W1t[n][k] = W1[k][n]
            ((ushort*)&o)[j] = f2bf(W1[k * 256 + n]);
        }
        *reinterpret_cast<ushort4*>(W1t + e) = o;
    } else if (b < 48) {
        const int e = ((b - 16) * 512 + t) * 4;     // W2t: 65536 elements
        ushort4 o;
        #pragma unroll
        for (int j = 0; j < 4; ++j) {
            const int ee = e + j;
            const int n = ee >> 8, k = ee & 255;    // W2t[n][k] = W2[k][n]
            ((ushort*)&o)[j] = f2bf(W2[k * 256 + n]);
        }
        *reinterpret_cast<ushort4*>(W2t + e) = o;
    } else {
        asum[t]       = 0.f;
        asum[512 + t] = 0.f;
    }
}

// ====== kernel 2: A = agg(x) @ W1 + b1 (agg fused in staging); BN partials -> asum ======
// 313 blocks x 512; tile 64(M) x 256(N), BK=64. xraw: 80 rows f32, 272B padded stride.
__global__ __launch_bounds__(512, 2) void k_fused1(const float* __restrict__ x,
    const ushort* __restrict__ W1t, const float* __restrict__ b1,
    ushort* __restrict__ A, float* __restrict__ asum)
{
    __shared__ alignas(16) char smem[21760 + 8192 + 32768];
    char* xr = smem;                    // 80 x 272B (f32, padded)
    char* As = smem + 21760;            // 64 x 128B (bf16, swizzled)
    char* Bs = smem + 21760 + 8192;     // 256 x 128B (bf16, swizzled)

    const int t = threadIdx.x;
    const int wave = t >> 6, lane = t & 63;
    const int wr = (wave >> 2) * 32;
    const int wc = (wave & 3) * 32;
    const int bm = blockIdx.x * 64;
    const float inv17 = 1.0f / 17.0f;
    f32x4 acc[2][2][2] = {};   // [ny][mi][ni]

    #pragma unroll
    for (int kt = 0; kt < 2; ++kt) {
        const int k0 = kt * 64;
        #pragma unroll
        for (int it = 0; it < 4; ++it) {   // stage B (async): 256x64 bf16, swizzled src
            const int cb = (it * 8 + wave) * 64 + lane;
            const int row = cb >> 3;
            const int lk = (cb & 7) ^ (row & 7);
            GLD16(W1t + (size_t)row * INFEAT + k0 + lk * 8, Bs + (it * 8 + wave) * 1024);
        }
        // reg-stage xraw: x rows [bm-8, bm+72) x 64 f32 cols, padded stride
        #pragma unroll
        for (int r3 = 0; r3 < 3; ++r3) {
            const int c = r3 * 512 + t;
            if (c < 1280) {
                const int row = c >> 4, cc = c & 15;
                const int rg = wrapN(bm - 8 + row);
                const float4 v = *reinterpret_cast<const float4*>(
                    x + (size_t)rg * INFEAT + k0 + cc * 4);
                *reinterpret_cast<float4*>(xr + row * 272 + cc * 16) = v;
            }
        }
        __syncthreads();
        {   // build As[row][64] = (1/17) * sum_{i=0..16} xraw[row+i]
            const int row = t >> 3, c8 = t & 7;
            float S[8] = {};
            #pragma unroll
            for (int i = 0; i < 17; ++i) {
                const float4 a = *reinterpret_cast<const float4*>(xr + (row + i) * 272 + c8 * 32);
                const float4 bq = *reinterpret_cast<const float4*>(xr + (row + i) * 272 + c8 * 32 + 16);
                S[0] += a.x;  S[1] += a.y;  S[2] += a.z;  S[3] += a.w;
                S[4] += bq.x; S[5] += bq.y; S[6] += bq.z; S[7] += bq.w;
            }
            u16x8 o;
            #pragma unroll
            for (int j = 0; j < 8; ++j) o[j] = f2bf(S[j] * inv17);
            *reinterpret_cast<u16x8*>(As + row * 128 + ((c8 ^ (row & 7)) * 16)) = o;
        }
        __syncthreads();
        #pragma unroll
        for (int kk = 0; kk < 2; ++kk) {
            const int klog = kk * 64 + ((lane >> 4) << 4);
            bf16x8 af[2];
            #pragma unroll
            for (int mi = 0; mi < 2; ++mi) {
                const int row = wr + mi * 16 + (lane & 15);
                af[mi] = *reinterpret_cast<const bf16x8*>(As + row * 128 + (klog ^ ((row & 7) << 4)));
            }
            #pragma unroll
            for (int ny = 0; ny < 2; ++ny)
                #pragma unroll
                for (int ni = 0; ni < 2; ++ni) {
                    const int row = ny * 128 + wc + ni * 16 + (lane & 15);
                    const bf16x8 bv = *reinterpret_cast<const bf16x8*>(Bs + row * 128 + (klog ^ ((row & 7) << 4)));
                    #pragma unroll
                    for (int mi = 0; mi < 2; ++mi)
                        acc[ny][mi][ni] = __builtin_amdgcn_mfma_f32_16x16x32_bf16(af[mi], bv, acc[ny][mi][ni], 0, 0, 0);
                }
        }
        __syncthreads();
    }

    // epilogue: bias, store A (bf16), BN partials -> global atomic accumulation
    float* sS  = (float*)smem;            // [8][64]
    float* s2S = (float*)(smem + 2048);   // [8][64]
    #pragma unroll
    for (int ny = 0; ny < 2; ++ny)
        #pragma unroll
        for (int ni = 0; ni < 2; ++ni) {
            const int colL = ny * 128 + wc + ni * 16 + (lane & 15);
            const float bv = b1[colL];
            float sv = 0.f, s2v = 0.f;
            #pragma unroll
            for (int mi = 0; mi < 2; ++mi)
                #pragma unroll
                for (int r = 0; r < 4; ++r) {
                    const int row = bm + wr + mi * 16 + ((lane >> 4) << 2) + r;
                    if (row < NN) {
                        const float val = acc[ny][mi][ni][r] + bv;
                        A[(size_t)row * 256 + colL] = f2bf(val);
                        sv += val; s2v += val * val;
                    }
                }
            sv  += __shfl_xor(sv, 16);  sv  += __shfl_xor(sv, 32);
            s2v += __shfl_xor(s2v, 16); s2v += __shfl_xor(s2v, 32);
            if (lane < 16) {
                sS [wave * 64 + ny * 32 + ni * 16 + lane] = sv;
                s2S[wave * 64 + ny * 32 + ni * 16 + lane] = s2v;
            }
        }
    __syncthreads();
    if (t < 256) {
        const int col = t;
        const int idx = (col >> 7) * 32 + ((col >> 4) & 1) * 16 + (col & 15);
        const int wcx = (col & 127) >> 5;
        atomicAdd(&asum[col],       sS [wcx * 64 + idx] + sS [(wcx + 4) * 64 + idx]);
        atomicAdd(&asum[512 + col], s2S[wcx * 64 + idx] + s2S[(wcx + 4) * 64 + idx]);
    }
}

// ===== kernel 3: h2 = relu( agg(relu(bn(A))) @ W2 + b2 ), dots -> u,w =====
// M=128 tile, 157 blocks. bn+relu at staging; rolling 2-row As-build;
// B half0 via GLD16, half1 reg-staged (latency hidden under As-build/MFMA h0).
__global__ __launch_bounds__(512, 2) void k_fused2(const ushort* __restrict__ A,
    const ushort* __restrict__ W2t, const float* __restrict__ gamma,
    const float* __restrict__ beta, const float* __restrict__ b2,
    const float* __restrict__ Wl, const float* __restrict__ asum,
    float* __restrict__ u, float* __restrict__ w)
{
    __shared__ alignas(16) char smem[23040 + 16384 + 16384 + 2048];
    char* xr   = smem;                            // 144 x 160B (bf16 bnrelu'd, padded)
    char* As   = smem + 23040;                    // 128 x 128B swizzled
    char* Bs   = smem + 23040 + 16384;            // 128 x 128B swizzled (one N-half)
    float* ssS = (float*)(smem + 23040 + 16384 + 16384);  // sc[256] | sh[256]

    const int t = threadIdx.x;
    const int wave = t >> 6, lane = t & 63;
    const int wr  = (wave >> 1) * 32;       // 4 row-quads
    const int wcx = (wave & 1);             // 2 col groups of 64 within 128-half
    const int bm = blockIdx.x * 128;
    const float inv17 = 1.0f / 17.0f;

    if (t < 256) {
        const float invn = 1.0f / (float)NN;
        const float mu  = asum[t] * invn;
        const float var = asum[512 + t] * invn - mu * mu;
        const float sc  = gamma[t] * rsqrtf(var + EPSF);
        ssS[t]       = sc;
        ssS[256 + t] = beta[t] - mu * sc;
    }
    __syncthreads();

    f32x4 acc[2][2][4] = {};   // [h][mi][ni]

    #pragma unroll
    for (int kt = 0; kt < 4; ++kt) {
        const int k0 = kt * 64;
        #pragma unroll
        for (int it = 0; it < 2; ++it) {   // stage B half0 (async): 128x64
            const int cb = (it * 8 + wave) * 64 + lane;
            const int row = cb >> 3;
            const int lk = (cb & 7) ^ (row & 7);
            GLD16(W2t + (size_t)row * 256 + k0 + lk * 8, Bs + (it * 8 + wave) * 1024);
        }
        // reg-stage xr = bnrelu(A rows [bm-8, bm+136), cols [k0,k0+64)): 1152 chunks
        #pragma unroll
        for (int r3 = 0; r3 < 3; ++r3) {
            const int c = r3 * 512 + t;
            if (c < 1152) {
                const int row = c >> 3, c8 = c & 7;
                const int rg = wrapN(bm - 8 + row);
                const int fb = k0 + c8 * 8;
                const u16x8 a = *reinterpret_cast<const u16x8*>(A + (size_t)rg * 256 + fb);
                const float4 sc0 = *reinterpret_cast<const float4*>(ssS + fb);
                const float4 sc1 = *reinterpret_cast<const float4*>(ssS + fb + 4);
                const float4 sh0 = *reinterpret_cast<const float4*>(ssS + 256 + fb);
                const float4 sh1 = *reinterpret_cast<const float4*>(ssS + 256 + fb + 4);
                u16x8 p;
                p[0] = f2bf(fmaxf(bf2f(a[0]) * sc0.x + sh0.x, 0.f));
                p[1] = f2bf(fmaxf(bf2f(a[1]) * sc0.y + sh0.y, 0.f));
                p[2] = f2bf(fmaxf(bf2f(a[2]) * sc0.z + sh0.z, 0.f));
                p[3] = f2bf(fmaxf(bf2f(a[3]) * sc0.w + sh0.w, 0.f));
                p[4] = f2bf(fmaxf(bf2f(a[4]) * sc1.x + sh1.x, 0.f));
                p[5] = f2bf(fmaxf(bf2f(a[5]) * sc1.y + sh1.y, 0.f));
                p[6] = f2bf(fmaxf(bf2f(a[6]) * sc1.z + sh1.z, 0.f));
                p[7] = f2bf(fmaxf(bf2f(a[7]) * sc1.w + sh1.w, 0.f));
                *reinterpret_cast<u16x8*>(xr + row * 160 + c8 * 16) = p;
            }
        }
        __syncthreads();

        // prefetch B half1 into regs (latency hides under As-build + MFMA h0)
        u16x8 bq0, bq1;
        {
            const int cb0 = t, cb1 = t + 512;
            bq0 = *reinterpret_cast<const u16x8*>(
                W2t + (size_t)(128 + (cb0 >> 3)) * 256 + k0 + (cb0 & 7) * 8);
            bq1 = *reinterpret_cast<const u16x8*>(
                W2t + (size_t)(128 + (cb1 >> 3)) * 256 + k0 + (cb1 & 7) * 8);
        }

        {   // build As: 2 rows/thread, rolling 17-tap
            const int q = t >> 3, c8 = t & 7;
            const int r0 = 2 * q;
            float S[8] = {};
            #pragma unroll
            for (int i = 0; i < 17; ++i) {
                const u16x8 h = *reinterpret_cast<const u16x8*>(xr + (r0 + i) * 160 + c8 * 16);
                #pragma unroll
                for (int j = 0; j < 8; ++j) S[j] += bf2f(h[j]);
            }
            u16x8 o;
            #pragma unroll
            for (int j = 0; j < 8; ++j) o[j] = f2bf(S[j] * inv17);
            *reinterpret_cast<u16x8*>(As + r0 * 128 + ((c8 ^ (r0 & 7)) * 16)) = o;
            const u16x8 ha = *reinterpret_cast<const u16x8*>(xr + (r0 + 17) * 160 + c8 * 16);
            const u16x8 hs = *reinterpret_cast<const u16x8*>(xr + r0 * 160 + c8 * 16);
            #pragma unroll
            for (int j = 0; j < 8; ++j) S[j] += bf2f(ha[j]) - bf2f(hs[j]);
            const int r1 = r0 + 1;
            #pragma unroll
            for (int j = 0; j < 8; ++j) o[j] = f2bf(S[j] * inv17);
            *reinterpret_cast<u16x8*>(As + r1 * 128 + ((c8 ^ (r1 & 7)) * 16)) = o;
        }
        __syncthreads();   // As ready, Bs(h0) ready

        #pragma unroll
        for (int kk = 0; kk < 2; ++kk) {   // MFMA h=0
            const int klog = kk * 64 + ((lane >> 4) << 4);
            bf16x8 af[2];
            #pragma unroll
            for (int mi = 0; mi < 2; ++mi) {
                const int row = wr + mi * 16 + (lane & 15);
                af[mi] = *reinterpret_cast<const bf16x8*>(As + row * 128 + (klog ^ ((row & 7) << 4)));
            }
            #pragma unroll
            for (int ni = 0; ni < 4; ++ni) {
                const int rl = wcx * 64 + ni * 16 + (lane & 15);
                const bf16x8 bv = *reinterpret_cast<const bf16x8*>(Bs + rl * 128 + (klog ^ ((rl & 7) << 4)));
                #pragma unroll
                for (int mi = 0; mi < 2; ++mi)
                    acc[0][mi][ni] = __builtin_amdgcn_mfma_f32_16x16x32_bf16(af[mi], bv, acc[0][mi][ni], 0, 0, 0);
            }
        }
        __syncthreads();   // Bs h0 consumed

        {   // write prefetched B half1 to LDS (swizzled)
            const int cb0 = t, cb1 = t + 512;
            const int r0w = cb0 >> 3, r1w = cb1 >> 3;
            *reinterpret_cast<u16x8*>(Bs + r0w * 128 + (((cb0 & 7) ^ (r0w & 7)) * 16)) = bq0;
            *reinterpret_cast<u16x8*>(Bs + r1w * 128 + (((cb1 & 7) ^ (r1w & 7)) * 16)) = bq1;
        }
        __syncthreads();   // Bs h1 ready

        #pragma unroll
        for (int kk = 0; kk < 2; ++kk) {   // MFMA h=1
            const int klog = kk * 64 + ((lane >> 4) << 4);
            bf16x8 af[2];
            #pragma unroll
            for (int mi = 0; mi < 2; ++mi) {
                const int row = wr + mi * 16 + (lane & 15);
                af[mi] = *reinterpret_cast<const bf16x8*>(As + row * 128 + (klog ^ ((row & 7) << 4)));
            }
            #pragma unroll
            for (int ni = 0; ni < 4; ++ni) {
                const int rl = wcx * 64 + ni * 16 + (lane & 15);
                const bf16x8 bv = *reinterpret_cast<const bf16x8*>(Bs + rl * 128 + (klog ^ ((rl & 7) << 4)));
                #pragma unroll
                for (int mi = 0; mi < 2; ++mi)
                    acc[1][mi][ni] = __builtin_amdgcn_mfma_f32_16x16x32_bf16(af[mi], bv, acc[1][mi][ni], 0, 0, 0);
            }
        }
        __syncthreads();   // end kt
    }

    // epilogue: relu + per-row dots with Wl -> u,w (full 256 cols in-block)
    float b2v[2][4], wav[2][4], wbv[2][4];
    #pragma unroll
    for (int h = 0; h < 2; ++h)
        #pragma unroll
        for (int ni = 0; ni < 4; ++ni) {
            const int col = h * 128 + wcx * 64 + ni * 16 + (lane & 15);
            b2v[h][ni] = b2[col];
            wav[h][ni] = Wl[col];
            wbv[h][ni] = Wl[256 + col];
        }
    float* uW = (float*)smem;            // [2][128]
    float* wW = (float*)(smem + 1024);   // [2][128]
    #pragma unroll
    for (int mi = 0; mi < 2; ++mi)
        #pragma unroll
        for (int r = 0; r < 4; ++r) {
            float pu = 0.f, pw = 0.f;
            #pragma unroll
            for (int h = 0; h < 2; ++h)
                #pragma unroll
                for (int ni = 0; ni < 4; ++ni) {
                    const float hv = fmaxf(acc[h][mi][ni][r] + b2v[h][ni], 0.f);
                    pu += hv * wav[h][ni];
                    pw += hv * wbv[h][ni];
                }
            pu += __shfl_xor(pu, 1); pu += __shfl_xor(pu, 2);
            pu += __shfl_xor(pu, 4); pu += __shfl_xor(pu, 8);
            pw += __shfl_xor(pw, 1); pw += __shfl_xor(pw, 2);
            pw += __shfl_xor(pw, 4); pw += __shfl_xor(pw, 8);
            if ((lane & 15) == 0) {
                const int rl = wr + mi * 16 + ((lane >> 4) << 2) + r;
                uW[wcx * 128 + rl] = pu;
                wW[wcx * 128 + rl] = pw;
            }
        }
    __syncthreads();
    if (t < 128) {
        const int row = bm + t;
        if (row < NN) {
            u[row] = uW[t] + uW[128 + t];
            w[row] = wW[t] + wW[128 + t];
        }
    }
}

// ============ kernel 4: P + edge outputs, 313 blocks x 512 (64 nodes each) ============
__global__ __launch_bounds__(512, 2) void k_out(const float* __restrict__ u,
    const float* __restrict__ w, const float* __restrict__ bl, float* __restrict__ out)
{
    const int bb = blockIdx.x, t = threadIdx.x;
    const int v0 = bb * 64;
    const float inv17 = 1.0f / 17.0f;
    __shared__ float uS[88];   // u[v0-8 .. v0+79]
    __shared__ float wS[72];   // w[v0 .. v0+71]
    __shared__ float PS[72];
    if (t < 88) uS[t] = u[wrapN(v0 - 8 + t)];
    else if (t < 160) wS[t - 88] = w[wrapN(v0 + (t - 88))];
    __syncthreads();
    if (t < 72) {
        float s = uS[t + 8] + 16.0f * wS[t];
        #pragma unroll
        for (int o = 1; o <= 8; ++o)
            s += uS[t + 8 + o] + uS[t + 8 - o];
        PS[t] = s;
    }
    __syncthreads();
    const float blv = bl[0];
    #pragma unroll
    for (int rr = 0; rr < 2; ++rr) {
        const int q = t + rr * 512;
        const int qq = q & 511;
        const int p = qq >> 3, off = qq & 7;
        const int v = v0 + p;
        if (v >= NN) continue;
        if (q < 512) {
            out[v * 8 + off] = sigmoidf_((PS[p] + wS[p + 1 + off]) * inv17 + blv);
        } else {
            out[NK + v * 8 + off] = sigmoidf_((PS[p + 1 + off] + wS[p]) * inv17 + blv);
        }
    }
}

// ---------------- launch ----------------
extern "C" void kernel_launch(void* const* d_in, const int* in_sizes, int n_in,
                              void* d_out, int out_size, void* d_ws, size_t ws_size,
                              hipStream_t stream)
{
    const float* x      = (const float*)d_in[0];
    const float* W1     = (const float*)d_in[1];
    const float* b1     = (const float*)d_in[2];
    const float* gamma1 = (const float*)d_in[3];
    const float* beta1  = (const float*)d_in[4];
    const float* W2     = (const float*)d_in[5];
    const float* b2     = (const float*)d_in[6];
    const float* Wl     = (const float*)d_in[7];
    const float* bl     = (const float*)d_in[8];
    float* out = (float*)d_out;

    float*    asum = (float*)d_ws;                   // [1024]
    float*    u    = asum + 1024;                    // [NN]
    float*    w    = u + NN;                         // [NN]
    ushort*   A    = (ushort*)(w + NN);              // [NN,256] bf16
    ushort*   W1t  = A + (size_t)NN * 256;           // [256,128]
    ushort*   W2t  = W1t + 256 * 128;                // [256,256]

    k_prep  <<<49,  512, 0, stream>>>(W1, W2, W1t, W2t, asum);
    k_fused1<<<NT1, 512, 0, stream>>>(x, W1t, b1, A, asum);
    k_fused2<<<NT2, 512, 0, stream>>>(A, W2t, gamma1, beta1, b2, Wl, asum, u, w);
    k_out   <<<NT1, 512, 0, stream>>>(u, w, bl, out);
}